// Round 2
// baseline (391.263 us; speedup 1.0000x reference)
//
#include <hip/hip_runtime.h>
#include <stdint.h>

#define T_STEPS 30
#define BTOT 65536
#define L2E 1.4426950408889634f

typedef __bf16 bf16_t;
typedef bf16_t bf16x8 __attribute__((ext_vector_type(8)));
typedef float f32x4 __attribute__((ext_vector_type(4)));

__device__ __forceinline__ float exp2_fast(float x) {
#if __has_builtin(__builtin_amdgcn_exp2f)
    return __builtin_amdgcn_exp2f(x);
#else
    return __expf(x * 0.6931471805599453f);
#endif
}
__device__ __forceinline__ float rcp_fast(float x) {
    return __builtin_amdgcn_rcpf(x);
}

// 3-wave layer pipeline: wave w owns LSTM layer w, weights live in VGPRs
// (2 matrices x 8 B-frags x 4 regs = 64 VGPRs/wave). Wave w computes its
// layer for t = s - w; h flows down through double-buffered LDS (barrier/step).
//
// MFMA 16x16x32 bf16 per 16-row batch tile:
//   A: row = lane&15 (batch), k = (lane>>4)*8 + j
//   B: pre-built frags in regs (k = (lane>>4)*8+j, n = tile*16 + (lane&15))
//   C/D: col = lane&15 (gate), row = (lane>>4)*4 + reg (batch)  [m89/m91]
// Gate tiles: 0,1 = i ; 2,3 = f ; 4,5 = g ; 6,7 = o  (PyTorch order)
// Bias is folded into the activation exp2 argument (pre-scaled by -L2E /
// -2*L2E), so acc starts from a literal-zero C operand: no per-cell init movs.
__global__ __launch_bounds__(192, 3) void lstm3_pipe(
    const float* __restrict__ X,
    const float* __restrict__ Wih0, const float* __restrict__ Whh0,
    const float* __restrict__ bih0, const float* __restrict__ bhh0,
    const float* __restrict__ Wih1, const float* __restrict__ Whh1,
    const float* __restrict__ bih1, const float* __restrict__ bhh1,
    const float* __restrict__ Wih2, const float* __restrict__ Whh2,
    const float* __restrict__ bih2, const float* __restrict__ bhh2,
    const float* __restrict__ W1, const float* __restrict__ b1,
    const float* __restrict__ W2, const float* __restrict__ b2,
    float* __restrict__ out)
{
    // 5 exchange buffers x 16 rows x stride 40 bf16 (80 B rows: 16B-aligned
    // b128 reads; 4 batch rows apart = 320 B = +16 banks -> write conflicts
    // drop 8-way -> 4-way). [0,1]=h0 dbuf, [2,3]=h1 dbuf, [4]=h2 self.
    __shared__ alignas(16) bf16_t xch[5 * 640];
    __shared__ float hfin[16][33];   // +1 pad: head reads conflict-free

    const int tid  = threadIdx.x;
    const int wave = tid >> 6;
    const int lane = tid & 63;
    const int lrow = lane & 15;
    const int kgrp = lane >> 4;
    const int b0   = blockIdx.x * 16;

    const float* Wih; const float* Whh; const float* bihp; const float* bhhp; int K;
    if (wave == 0)      { Wih = Wih0; Whh = Whh0; bihp = bih0; bhhp = bhh0; K = 3;  }
    else if (wave == 1) { Wih = Wih1; Whh = Whh1; bihp = bih1; bhhp = bhh1; K = 32; }
    else                { Wih = Wih2; Whh = Whh2; bihp = bih2; bhhp = bhh2; K = 32; }

    // ---- one-time: build this wave's B-fragments in registers ----
    bf16x8 wih[8], whh[8];
    float bs[8];   // pre-scaled bias: -L2E*b (sigmoid tiles), -2*L2E*b (g tiles)
#pragma unroll
    for (int tl = 0; tl < 8; ++tl) {
        const int n = tl * 16 + lrow;
        bf16x8 fi, fh;
        if (K == 32) {
            const float* p = Wih + n * 32 + kgrp * 8;
#pragma unroll
            for (int j = 0; j < 8; ++j) fi[j] = (bf16_t)p[j];
        } else {
#pragma unroll
            for (int j = 0; j < 8; ++j) {
                const int k = kgrp * 8 + j;
                fi[j] = (k < 3) ? (bf16_t)Wih[n * 3 + k] : (bf16_t)(0.0f);
            }
        }
        const float* q = Whh + n * 32 + kgrp * 8;
#pragma unroll
        for (int j = 0; j < 8; ++j) fh[j] = (bf16_t)q[j];
        wih[tl] = fi;
        whh[tl] = fh;
        const float b = bihp[n] + bhhp[n];
        bs[tl] = b * (((tl >> 1) == 2) ? (-2.0f * L2E) : (-L2E));
    }

    float cst[2][4];
    float h2keep[2][4];
#pragma unroll
    for (int mt = 0; mt < 2; ++mt)
#pragma unroll
        for (int r = 0; r < 4; ++r) { cst[mt][r] = 0.0f; h2keep[mt][r] = 0.0f; }

    bf16x8 ah;
#pragma unroll
    for (int j = 0; j < 8; ++j) ah[j] = (bf16_t)(0.0f);

    const float* xlane = X + (size_t)(b0 + lrow) * (T_STEPS * 3);
    float cx0 = 0.0f, cx1 = 0.0f, cx2 = 0.0f;
    if (wave == 0) { cx0 = xlane[0]; cx1 = xlane[1]; cx2 = xlane[2]; }

    const int wslot = (wave == 0) ? 0 : 2;   // parity-indexed for waves 0,1
    const int rslot = (wave == 1) ? 0 : 2;   // waves 1,2 read upstream dbuf

    for (int s = 0; s < T_STEPS + 2; ++s) {
        const int tw = s - wave;             // this wave's timestep
        if (tw >= 0 && tw < T_STEPS) {
            const int par = tw & 1;
            bf16x8 ain;
            if (wave == 0) {
                // prefetch next x under this step's compute
                const int tn = (tw < T_STEPS - 1) ? tw + 1 : T_STEPS - 1;
                const float nx0 = xlane[tn * 3 + 0];
                const float nx1 = xlane[tn * 3 + 1];
                const float nx2 = xlane[tn * 3 + 2];
#pragma unroll
                for (int j = 0; j < 8; ++j) ain[j] = (bf16_t)(0.0f);
                if (kgrp == 0) {
                    ain[0] = (bf16_t)cx0; ain[1] = (bf16_t)cx1; ain[2] = (bf16_t)cx2;
                }
                cx0 = nx0; cx1 = nx1; cx2 = nx2;
            } else {
                // h from the layer below, written last step (barrier-separated)
                ain = *(const bf16x8*)(xch + (rslot + par) * 640 + lrow * 40 + (kgrp << 3));
            }

            f32x4 acc[8];
#pragma unroll
            for (int tl = 0; tl < 8; ++tl) {
                f32x4 z; z[0] = 0.0f; z[1] = 0.0f; z[2] = 0.0f; z[3] = 0.0f;
                acc[tl] = __builtin_amdgcn_mfma_f32_16x16x32_bf16(ain, wih[tl], z, 0, 0, 0);
            }
#pragma unroll
            for (int tl = 0; tl < 8; ++tl)
                acc[tl] = __builtin_amdgcn_mfma_f32_16x16x32_bf16(ah, whh[tl], acc[tl], 0, 0, 0);

            bf16_t* wb = xch + (((wave == 2) ? 4 : (wslot + par)) * 640);
            const bool sv = (wave == 2) && (tw == T_STEPS - 1);
#pragma unroll
            for (int mt = 0; mt < 2; ++mt) {
#pragma unroll
                for (int r = 0; r < 4; ++r) {
                    const float iv = rcp_fast(1.0f + exp2_fast(acc[0 + mt][r] * (-L2E) + bs[0 + mt]));
                    const float fv = rcp_fast(1.0f + exp2_fast(acc[2 + mt][r] * (-L2E) + bs[2 + mt]));
                    const float ge = exp2_fast(acc[4 + mt][r] * (-2.0f * L2E) + bs[4 + mt]);
                    const float gv = 2.0f * rcp_fast(1.0f + ge) - 1.0f;
                    const float ov = rcp_fast(1.0f + exp2_fast(acc[6 + mt][r] * (-L2E) + bs[6 + mt]));
                    const float cc = fv * cst[mt][r] + iv * gv;
                    cst[mt][r] = cc;
                    const float te = exp2_fast(cc * (-2.0f * L2E));
                    const float th = 2.0f * rcp_fast(1.0f + te) - 1.0f;
                    const float hv = ov * th;
                    if (sv) h2keep[mt][r] = hv;
                    wb[(kgrp * 4 + r) * 40 + mt * 16 + lrow] = (bf16_t)hv;  // [batch][h]
                }
            }
            // reload own h_t as next step's A-frag (intra-wave, in-order DS)
            ah = *(const bf16x8*)(wb + lrow * 40 + (kgrp << 3));
        }
        __syncthreads();
    }

    // ---- head: out = (h2 @ W1^T + b1) @ W2^T + b2, fp32, wave2 only ----
    if (wave == 2) {
#pragma unroll
        for (int mt = 0; mt < 2; ++mt)
#pragma unroll
            for (int r = 0; r < 4; ++r)
                hfin[kgrp * 4 + r][mt * 16 + lrow] = h2keep[mt][r];

        if (lane < 16) {
            float hv[32];
#pragma unroll
            for (int k = 0; k < 32; ++k) hv[k] = hfin[lane][k];
            float y1[16];
#pragma unroll
            for (int o = 0; o < 16; ++o) {
                float a = b1[o];
#pragma unroll
                for (int k = 0; k < 32; ++k) a += hv[k] * W1[o * 32 + k];
                y1[o] = a;
            }
            const int b = b0 + lane;
#pragma unroll
            for (int q = 0; q < 7; ++q) {
                float a = b2[q];
#pragma unroll
                for (int o = 0; o < 16; ++o) a += y1[o] * W2[q * 16 + o];
                out[b * 7 + q] = a;
            }
        }
    }
}

extern "C" void kernel_launch(void* const* d_in, const int* in_sizes, int n_in,
                              void* d_out, int out_size, void* d_ws, size_t ws_size,
                              hipStream_t stream) {
    (void)in_sizes; (void)n_in; (void)d_ws; (void)ws_size; (void)out_size;
    const float* X    = (const float*)d_in[0];
    const float* Wih0 = (const float*)d_in[1];
    const float* Whh0 = (const float*)d_in[2];
    const float* bih0 = (const float*)d_in[3];
    const float* bhh0 = (const float*)d_in[4];
    const float* Wih1 = (const float*)d_in[5];
    const float* Whh1 = (const float*)d_in[6];
    const float* bih1 = (const float*)d_in[7];
    const float* bhh1 = (const float*)d_in[8];
    const float* Wih2 = (const float*)d_in[9];
    const float* Whh2 = (const float*)d_in[10];
    const float* bih2 = (const float*)d_in[11];
    const float* bhh2 = (const float*)d_in[12];
    const float* W1   = (const float*)d_in[13];
    const float* b1   = (const float*)d_in[14];
    const float* W2   = (const float*)d_in[15];
    const float* b2   = (const float*)d_in[16];
    float* out = (float*)d_out;

    dim3 grid(BTOT / 16), block(192);
    hipLaunchKernelGGL(lstm3_pipe, grid, block, 0, stream,
                       X, Wih0, Whh0, bih0, bhh0, Wih1, Whh1, bih1, bhh1,
                       Wih2, Whh2, bih2, bhh2, W1, b1, W2, b2, out);
}

// Round 3
// 294.746 us; speedup vs baseline: 1.3275x; 1.3275x over previous
//
#include <hip/hip_runtime.h>
#include <stdint.h>

#define T_STEPS 30
#define BTOT 65536
#define L2E 1.4426950408889634f

typedef __bf16 bf16_t;
typedef bf16_t bf16x8 __attribute__((ext_vector_type(8)));
typedef float f32x4 __attribute__((ext_vector_type(4)));

__device__ __forceinline__ float exp2_fast(float x) {
#if __has_builtin(__builtin_amdgcn_exp2f)
    return __builtin_amdgcn_exp2f(x);
#else
    return __expf(x * 0.6931471805599453f);
#endif
}
__device__ __forceinline__ float rcp_fast(float x) {
    return __builtin_amdgcn_rcpf(x);
}

// 8 independent waves per 512-thread block; each wave owns 16 batch rows and
// runs all 3 layers x 30 steps with no barriers after weight staging.
// Weights: LDS B-fragments shared by all waves (staged once, 48 KB).
// MFMA 16x16x32 bf16:
//   A (16 batch x 32 k): row = lane&15, k = (lane>>4)*8 + j
//   B (32 k x gates):    frag[lane] = W[tile*16 + (lane&15)][(lane>>4)*8+j]
//   C/D: col(gate) = lane&15, row(batch) = (lane>>4)*4 + reg   [m89/m91]
// Gate tiles: 0,1=i; 2,3=f; 4,5=g; 6,7=o (PyTorch order).
//
// Fused activation (7 trans/element instead of 10):
//   A=e^{-ai}, F=e^{-af}, B=e^{-2ag}, O=e^{-ao}  (bias pre-folded, exp2 form)
//   c' = (c*(1+A)*(1+B) + (1-B)*(1+F)) / ((1+F)*(1+A)*(1+B))   .. 1 rcp
//   h  = (1-C)/((1+O)*(1+C)),  C=e^{-2c'}                      .. 1 rcp
template <int LI, bool SAVE>
__device__ __forceinline__ void cell(
    int lane, int lrow, int kgrp,
    const bf16_t* __restrict__ wb,      // laundered LDS weight-fragment base
    const float (&bs)[3][8],            // pre-scaled biases per gate tile
    bf16x8 ain,                         // A-frag: x or h from layer below
    bf16x8& ah,                         // in: h_{t-1} A-frag ; out: h_t
    float (&cst)[3][2][4],
    float (&hsave)[2][4],
    bf16_t* __restrict__ hb)            // wave-private exchange, row stride 40
{
    constexpr int WIH_OFF = ((LI == 0) ? 0 : (LI == 1) ? 2 : 4) * 4096;
    constexpr int WHH_OFF = WIH_OFF + 4096;

    f32x4 z;
    z[0] = 0.0f; z[1] = 0.0f; z[2] = 0.0f; z[3] = 0.0f;
    f32x4 acc[8];
#pragma unroll
    for (int tl = 0; tl < 8; ++tl) {
        bf16x8 bfr = *(const bf16x8*)(wb + WIH_OFF + (tl << 9) + (lane << 3));
        acc[tl] = __builtin_amdgcn_mfma_f32_16x16x32_bf16(ain, bfr, z, 0, 0, 0);
    }
#pragma unroll
    for (int tl = 0; tl < 8; ++tl) {
        bf16x8 bfr = *(const bf16x8*)(wb + WHH_OFF + (tl << 9) + (lane << 3));
        acc[tl] = __builtin_amdgcn_mfma_f32_16x16x32_bf16(ah, bfr, acc[tl], 0, 0, 0);
    }
#pragma unroll
    for (int mt = 0; mt < 2; ++mt) {
#pragma unroll
        for (int r = 0; r < 4; ++r) {
            const float Ae = exp2_fast(acc[0 + mt][r] * (-L2E) + bs[LI][0 + mt]);
            const float Fe = exp2_fast(acc[2 + mt][r] * (-L2E) + bs[LI][2 + mt]);
            const float Be = exp2_fast(acc[4 + mt][r] * (-2.0f * L2E) + bs[LI][4 + mt]);
            const float Oe = exp2_fast(acc[6 + mt][r] * (-L2E) + bs[LI][6 + mt]);
            const float pA = 1.0f + Ae, pF = 1.0f + Fe, pB = 1.0f + Be, pO = 1.0f + Oe;
            const float nB = 1.0f - Be;
            const float t1 = pA * pB;
            const float D  = t1 * pF;
            const float N  = __builtin_fmaf(cst[LI][mt][r], t1, nB * pF);
            const float cc = N * rcp_fast(D);
            cst[LI][mt][r] = cc;
            const float Ce = exp2_fast(cc * (-2.0f * L2E));
            const float pC = 1.0f + Ce, nC = 1.0f - Ce;
            const float hv = nC * rcp_fast(pO * pC);
            if (SAVE) hsave[mt][r] = hv;
            hb[(kgrp * 4 + r) * 40 + mt * 16 + lrow] = (bf16_t)hv;
        }
    }
    // reload own h_t as A-frag (intra-wave, in-order DS pipe: no barrier)
    ah = *(const bf16x8*)(hb + lrow * 40 + (kgrp << 3));
}

__global__ __launch_bounds__(512, 4) void lstm3_fused(
    const float* __restrict__ X,
    const float* __restrict__ Wih0, const float* __restrict__ Whh0,
    const float* __restrict__ bih0, const float* __restrict__ bhh0,
    const float* __restrict__ Wih1, const float* __restrict__ Whh1,
    const float* __restrict__ bih1, const float* __restrict__ bhh1,
    const float* __restrict__ Wih2, const float* __restrict__ Whh2,
    const float* __restrict__ bih2, const float* __restrict__ bhh2,
    const float* __restrict__ W1, const float* __restrict__ b1,
    const float* __restrict__ W2, const float* __restrict__ b2,
    float* __restrict__ out)
{
    __shared__ alignas(16) bf16_t wfrag[6 * 4096];   // 48 KB, shared by 8 waves
    __shared__ float bias_s[3][128];
    __shared__ alignas(16) bf16_t hbuf[8][16 * 40];  // per-wave, stride 40
    __shared__ float hfin[8][16][33];                // +1 pad: head reads clean

    const int tid = threadIdx.x;

    auto stage = [&](int mat, const float* __restrict__ w, int K) {
        for (int p = tid; p < 4096; p += 512) {
            const int tile = p >> 9;
            const int r = p & 511;
            const int ln = r >> 3;
            const int j = r & 7;
            const int k = ((ln >> 4) << 3) + j;
            const int n = (tile << 4) + (ln & 15);
            const float v = (k < K) ? w[n * K + k] : 0.0f;
            wfrag[mat * 4096 + p] = (bf16_t)v;
        }
    };
    stage(0, Wih0, 3);
    stage(1, Whh0, 32);
    stage(2, Wih1, 32);
    stage(3, Whh1, 32);
    stage(4, Wih2, 32);
    stage(5, Whh2, 32);
    for (int p = tid; p < 384; p += 512) {
        const int l = p >> 7, n = p & 127;
        float v;
        if (l == 0)      v = bih0[n] + bhh0[n];
        else if (l == 1) v = bih1[n] + bhh1[n];
        else             v = bih2[n] + bhh2[n];
        bias_s[l][n] = v;
    }
    __syncthreads();

    const int wave = tid >> 6;
    const int lane = tid & 63;
    const int lrow = lane & 15;
    const int kgrp = lane >> 4;
    const int b0   = blockIdx.x * 128 + wave * 16;

    // pre-scaled biases: -L2E*b for sigmoid tiles, -2*L2E*b for g tiles
    float bs[3][8];
#pragma unroll
    for (int l = 0; l < 3; ++l)
#pragma unroll
        for (int tl = 0; tl < 8; ++tl)
            bs[l][tl] = bias_s[l][tl * 16 + lrow] *
                        (((tl >> 1) == 2) ? (-2.0f * L2E) : (-L2E));

    float cst[3][2][4];
    float h2keep[2][4];
#pragma unroll
    for (int l = 0; l < 3; ++l)
#pragma unroll
        for (int mt = 0; mt < 2; ++mt)
#pragma unroll
            for (int r = 0; r < 4; ++r) cst[l][mt][r] = 0.0f;
#pragma unroll
    for (int mt = 0; mt < 2; ++mt)
#pragma unroll
        for (int r = 0; r < 4; ++r) h2keep[mt][r] = 0.0f;

    bf16x8 ah0, ah1, ah2;
#pragma unroll
    for (int j = 0; j < 8; ++j) {
        ah0[j] = (bf16_t)0.0f; ah1[j] = (bf16_t)0.0f; ah2[j] = (bf16_t)0.0f;
    }

    bf16_t* hb = &hbuf[wave][0];

    const float* xlane = X + (size_t)(b0 + lrow) * (T_STEPS * 3);
    float cx0 = xlane[0], cx1 = xlane[1], cx2 = xlane[2];

    for (int t = 0; t < T_STEPS; ++t) {
        const int tn = (t < T_STEPS - 1) ? (t + 1) : (T_STEPS - 1);
        const float nx0 = xlane[tn * 3 + 0];
        const float nx1 = xlane[tn * 3 + 1];
        const float nx2 = xlane[tn * 3 + 2];

        // launder LDS base each iteration so LICM can't hoist 48 weight frags
        unsigned lz = 0;
        asm volatile("" : "+v"(lz));
        const bf16_t* wbt = wfrag + lz;

        bf16x8 ax;
#pragma unroll
        for (int j = 0; j < 8; ++j) ax[j] = (bf16_t)0.0f;
        if (kgrp == 0) { ax[0] = (bf16_t)cx0; ax[1] = (bf16_t)cx1; ax[2] = (bf16_t)cx2; }

        cell<0, false>(lane, lrow, kgrp, wbt, bs, ax,  ah0, cst, h2keep, hb);
        cell<1, false>(lane, lrow, kgrp, wbt, bs, ah0, ah1, cst, h2keep, hb);
        cell<2, true >(lane, lrow, kgrp, wbt, bs, ah1, ah2, cst, h2keep, hb);

        cx0 = nx0; cx1 = nx1; cx2 = nx2;
    }

    // ---- head: out = (h2 @ W1^T + b1) @ W2^T + b2, fp32 ----
#pragma unroll
    for (int mt = 0; mt < 2; ++mt)
#pragma unroll
        for (int r = 0; r < 4; ++r)
            hfin[wave][kgrp * 4 + r][mt * 16 + lrow] = h2keep[mt][r];

    if (lane < 16) {
        float hv[32];
#pragma unroll
        for (int k = 0; k < 32; ++k) hv[k] = hfin[wave][lane][k];
        float y1[16];
#pragma unroll
        for (int o = 0; o < 16; ++o) {
            float a = b1[o];
#pragma unroll
            for (int k = 0; k < 32; ++k) a += hv[k] * W1[o * 32 + k];
            y1[o] = a;
        }
        const int b = b0 + lane;
#pragma unroll
        for (int q = 0; q < 7; ++q) {
            float a = b2[q];
#pragma unroll
            for (int o = 0; o < 16; ++o) a += y1[o] * W2[q * 16 + o];
            out[b * 7 + q] = a;
        }
    }
}

extern "C" void kernel_launch(void* const* d_in, const int* in_sizes, int n_in,
                              void* d_out, int out_size, void* d_ws, size_t ws_size,
                              hipStream_t stream) {
    (void)in_sizes; (void)n_in; (void)d_ws; (void)ws_size; (void)out_size;
    const float* X    = (const float*)d_in[0];
    const float* Wih0 = (const float*)d_in[1];
    const float* Whh0 = (const float*)d_in[2];
    const float* bih0 = (const float*)d_in[3];
    const float* bhh0 = (const float*)d_in[4];
    const float* Wih1 = (const float*)d_in[5];
    const float* Whh1 = (const float*)d_in[6];
    const float* bih1 = (const float*)d_in[7];
    const float* bhh1 = (const float*)d_in[8];
    const float* Wih2 = (const float*)d_in[9];
    const float* Whh2 = (const float*)d_in[10];
    const float* bih2 = (const float*)d_in[11];
    const float* bhh2 = (const float*)d_in[12];
    const float* W1   = (const float*)d_in[13];
    const float* b1   = (const float*)d_in[14];
    const float* W2   = (const float*)d_in[15];
    const float* b2   = (const float*)d_in[16];
    float* out = (float*)d_out;

    dim3 grid(BTOT / 128), block(512);
    hipLaunchKernelGGL(lstm3_fused, grid, block, 0, stream,
                       X, Wih0, Whh0, bih0, bhh0, Wih1, Whh1, bih1, bhh1,
                       Wih2, Whh2, bih2, bhh2, W1, b1, W2, b2, out);
}